// Round 20
// baseline (56.270 us; speedup 1.0000x reference)
//
#include <hip/hip_runtime.h>
#include <hip/hip_bf16.h>

// QueryGrouper: ball_query (first-K-in-index-order within radius) + grouping.
// B=4, N=8192, M=2048, C=128, K=32, radius=0.1, use_xyz from out_size.
//
// R20: x-binned ball. Brute-force ball plateaued at ~25us across 5 designs
// (issue-bound, VALUBusy 72%); micro-cuts were null (R19). Remaining lever is
// WORK: r=0.1 => only ~26% of points can hit a query (x-window). Bin points
// by x into 16 bins (contiguous ranges), scan only [qx-r, qx+r] bins
// (~2150 pts vs 8192), collect hits unordered, 64-lane bitonic sort by
// original index = JAX sort(cand)[:K] exactly. hcnt>64 (P~1e-7): exact
// index-order rescan fallback. d2 bit-identical (binned coords copied).
// Gather: R12-validated one-pass (write roofline: FETCH 9.3MB, 6.26TB/s).

#define K_NEIGH 32
// f32(0.010000000000000002) — matches JAX weak-typed radius*radius bit-exactly.
#define R2_F32 0.009999999776482582f
#define CCH 128
#define NPTS 8192
#define MQ 2048
#define NBIN 16

// ---- bin points by x: (B,3,N) -> binned (B,N) float4 {x,y,z,idx}, binStart (B,17)
__global__ __launch_bounds__(1024) void bin_points_kernel(
    const float* __restrict__ xyz,
    float4* __restrict__ binned,
    int* __restrict__ binStart)
{
    __shared__ int hist[NBIN];
    __shared__ int start[NBIN + 1];
    __shared__ int cursor[NBIN];
    const int t = threadIdx.x;
    const int b = blockIdx.x;
    const float* x0 = xyz + (size_t)b * 3 * NPTS;
    const float* x1 = x0 + NPTS;
    const float* x2 = x1 + NPTS;

    if (t < NBIN) hist[t] = 0;
    __syncthreads();
    #pragma unroll
    for (int k = 0; k < NPTS / 1024; ++k) {
        const int i = t + k * 1024;
        int bin = (int)floorf(x0[i] * 16.0f);
        bin = bin < 0 ? 0 : (bin > 15 ? 15 : bin);
        atomicAdd(&hist[bin], 1);
    }
    __syncthreads();
    if (t == 0) {
        int acc = 0;
        for (int k = 0; k < NBIN; ++k) { start[k] = acc; cursor[k] = acc; acc += hist[k]; }
        start[NBIN] = acc;
    }
    __syncthreads();
    #pragma unroll
    for (int k = 0; k < NPTS / 1024; ++k) {
        const int i = t + k * 1024;
        const float x = x0[i];
        int bin = (int)floorf(x * 16.0f);
        bin = bin < 0 ? 0 : (bin > 15 ? 15 : bin);
        const int slot = atomicAdd(&cursor[bin], 1);
        float4 p;
        p.x = x; p.y = x1[i]; p.z = x2[i]; p.w = __int_as_float(i);
        binned[(size_t)b * NPTS + slot] = p;
    }
    if (t <= NBIN) binStart[b * (NBIN + 1) + t] = start[t];
}

// ---- ball: 1 query/wave, binned-range scan + bitonic-64 index sort ----
__global__ __launch_bounds__(256, 8) void ball_binned_kernel(
    const float* __restrict__ xyz, const float* __restrict__ new_xyz,
    const float4* __restrict__ binned, const int* __restrict__ binStart,
    int* __restrict__ idxb, float* __restrict__ out0, float* __restrict__ out1,
    int use_xyz)
{
    __shared__ int sidx[4][64];
    const int wav  = threadIdx.x >> 6;
    const int lane = threadIdx.x & 63;
    const int q = blockIdx.x * 4 + wav;
    const int b = q >> 11;               // MQ = 2048
    const int m = q & (MQ - 1);

    const float* x0 = xyz + (size_t)b * 3 * NPTS;
    const float* x1 = x0 + NPTS;
    const float* x2 = x1 + NPTS;
    const float* nb = new_xyz + (size_t)b * 3 * MQ;
    const float qx = nb[m];
    const float qy = nb[MQ + m];
    const float qz = nb[2 * MQ + m];

    // conservative bin window (1e-6 margin covers f32 rounding of the d2 test)
    int lo = (int)floorf((qx - 0.100001f) * 16.0f);
    int hi = (int)floorf((qx + 0.100001f) * 16.0f);
    lo = lo < 0 ? 0 : (lo > 15 ? 15 : lo);
    hi = hi < 0 ? 0 : (hi > 15 ? 15 : hi);
    const int s = binStart[b * (NBIN + 1) + lo];
    const int e = binStart[b * (NBIN + 1) + hi + 1];
    const float4* bp = binned + (size_t)b * NPTS;

    const unsigned long long below = (1ull << lane) - 1ull;
    int hcnt = 0;
    for (int g = s; g < e; g += 64) {
        const int i = g + lane;
        bool hit = false;
        int oi = 0;
        if (i < e) {
            const float4 p = bp[i];
            // match JAX: sub, square (no FMA), left-to-right sum, all f32 RN
            const float d2 = __fadd_rn(__fadd_rn(__fmul_rn(p.x - qx, p.x - qx),
                                                 __fmul_rn(p.y - qy, p.y - qy)),
                                       __fmul_rn(p.z - qz, p.z - qz));
            hit = d2 < R2_F32;
            oi = __float_as_int(p.w);
        }
        const unsigned long long mk = __ballot(hit);
        if (hit) {
            const int pos = hcnt + (int)__popcll(mk & below);
            if (pos < 64) sidx[wav][pos] = oi;
        }
        hcnt += (int)__popcll(mk);       // wave-uniform
    }

    asm volatile("s_waitcnt lgkmcnt(0)" ::: "memory");

    int j = 0;
    if (hcnt <= 64) {
        int v = (lane < hcnt) ? sidx[wav][lane] : 0x7FFFFFFF;
        // bitonic sort 64 ascending (canonical shfl_xor network)
        #pragma unroll
        for (int k = 2; k <= 64; k <<= 1) {
            #pragma unroll
            for (int jj = k >> 1; jj > 0; jj >>= 1) {
                const int other = __shfl_xor(v, jj, 64);
                const bool up   = ((lane & k) == 0);
                const bool lowr = ((lane & jj) == 0);
                const int mn = v < other ? v : other;
                const int mx = v < other ? other : v;
                v = (lowr == up) ? mn : mx;
            }
        }
        const int v0  = __shfl(v, 0, 64);            // smallest index = first hit
        const int pad = (hcnt > 0) ? v0 : 0;
        j = (lane < hcnt) ? v : pad;
    } else {
        // rare (P~1e-7/query): exact index-order rescan for this query
        int cnt = 0, ff = 0;
        for (int t0 = 0; t0 < NPTS; t0 += 64) {
            const int i = t0 + lane;
            const float dx = x0[i] - qx;
            const float dy = x1[i] - qy;
            const float dz = x2[i] - qz;
            const float d2 = __fadd_rn(__fadd_rn(__fmul_rn(dx, dx), __fmul_rn(dy, dy)),
                                       __fmul_rn(dz, dz));
            const bool in_ball = d2 < R2_F32;
            const unsigned long long mask = __ballot(in_ball);
            if (mask) {
                if (cnt == 0) ff = t0 + (__ffsll(mask) - 1);
                if (in_ball) {
                    const int pos = cnt + __popcll(mask & below);
                    if (pos < K_NEIGH) sidx[wav][pos] = i;
                }
                cnt += __popcll(mask);
                if (cnt >= K_NEIGH) break;
            }
        }
        asm volatile("s_waitcnt lgkmcnt(0)" ::: "memory");
        j = (lane < cnt) ? sidx[wav][lane] : ff;
    }

    if (lane < K_NEIGH) {
        idxb[(size_t)q * K_NEIGH + lane] = j;
        const float gx = x0[j] - qx;
        const float gy = x1[j] - qy;
        const float gz = x2[j] - qz;
        const size_t MK = (size_t)MQ * K_NEIGH;
        const size_t o1 = (size_t)b * 3 * MK + (size_t)m * K_NEIGH + lane;
        out1[o1]          = gx;
        out1[o1 + MK]     = gy;
        out1[o1 + 2 * MK] = gz;
        if (use_xyz) {
            const size_t o0 = (size_t)b * (CCH + 3) * MK + (size_t)m * K_NEIGH + lane;
            out0[o0]          = gx;
            out0[o0 + MK]     = gy;
            out0[o0 + 2 * MK] = gz;
        }
    }
}

// ---- fallback ball (any shape): global loads, 1 query/wave ----
__global__ __launch_bounds__(256) void ball_query_xyz_kernel(
    const float* __restrict__ xyz, const float* __restrict__ new_xyz,
    int* __restrict__ idxb, float* __restrict__ out0, float* __restrict__ out1,
    int N, int M, int C, int use_xyz)
{
    __shared__ int lidx[4][K_NEIGH];
    const int wave = threadIdx.x >> 6;
    const int lane = threadIdx.x & 63;
    const int q = blockIdx.x * 4 + wave;
    const int b = q / M;
    const int m = q - b * M;

    const float* xb = xyz + (size_t)b * 3 * N;
    const float* x0 = xb;
    const float* x1 = xb + N;
    const float* x2 = xb + 2 * N;
    const float* nb = new_xyz + (size_t)b * 3 * M;
    const float qx = nb[m];
    const float qy = nb[M + m];
    const float qz = nb[2 * M + m];

    int cnt = 0;
    int ff  = 0;
    const unsigned long long below = (1ull << lane) - 1ull;

    for (int t0 = 0; t0 < N; t0 += 64) {
        const int i = t0 + lane;
        const float dx = x0[i] - qx;
        const float dy = x1[i] - qy;
        const float dz = x2[i] - qz;
        const float d2 = __fadd_rn(__fadd_rn(__fmul_rn(dx, dx), __fmul_rn(dy, dy)),
                                   __fmul_rn(dz, dz));
        const bool in_ball = d2 < R2_F32;
        const unsigned long long mask = __ballot(in_ball);
        if (mask) {
            if (cnt == 0) ff = t0 + (__ffsll(mask) - 1);
            if (in_ball) {
                const int pos = cnt + __popcll(mask & below);
                if (pos < K_NEIGH) lidx[wave][pos] = i;
            }
            cnt += __popcll(mask);
            if (cnt >= K_NEIGH) break;
        }
    }

    asm volatile("s_waitcnt lgkmcnt(0)" ::: "memory");

    if (lane < K_NEIGH) {
        const int j = (lane < cnt) ? lidx[wave][lane] : ff;
        idxb[(size_t)q * K_NEIGH + lane] = j;
        const float gx = x0[j] - qx;
        const float gy = x1[j] - qy;
        const float gz = x2[j] - qz;
        const size_t MK = (size_t)M * K_NEIGH;
        const size_t o1 = (size_t)b * 3 * MK + (size_t)m * K_NEIGH + lane;
        out1[o1]          = gx;
        out1[o1 + MK]     = gy;
        out1[o1 + 2 * MK] = gz;
        if (use_xyz) {
            const size_t o0 = (size_t)b * (C + 3) * MK + (size_t)m * K_NEIGH + lane;
            out0[o0]          = gx;
            out0[o0 + MK]     = gy;
            out0[o0 + 2 * MK] = gz;
        }
    }
}

// Fixed geometry: B=4, N=8192, M=2048, C=128. Grid = 256 blocks x 1024 thr.
// One pass, plain float4 stores (R12-validated: runs at write roofline).
__global__ __launch_bounds__(1024, 4) void gather_onepass_kernel(
    const float* __restrict__ feat,  // (B,C,N)
    const int* __restrict__ idxb,    // (B*M,K)
    float* __restrict__ out0,        // (B,CO,M,K)
    int use_xyz)
{
    __shared__ float sf[2 * NPTS];   // 64 KB: [0,N) = ch c0, [N,2N) = ch c0+1

    const int t   = threadIdx.x;
    const int bid = blockIdx.x;
    const int b   = (bid & 7) >> 1;                 // 0..3
    const int cg  = ((bid >> 3) << 1) | (bid & 1);  // 0..63
    const int c0  = cg * 2;

    // ---- Phase A: idx prefetch (regs) + feat stage (LDS) ----
    const int4* ip4 = (const int4*)(idxb + (size_t)b * MQ * K_NEIGH);
    int4 jj[16];
    #pragma unroll
    for (int i = 0; i < 16; ++i) jj[i] = ip4[i * 1024 + t];

    const float4* fv = (const float4*)(feat + ((size_t)b * CCH + c0) * NPTS);
    #pragma unroll
    for (int r = 0; r < 4; ++r)
        ((float4*)sf)[t + r * 1024] = fv[t + r * 1024];
    __syncthreads();

    // ---- Phase B: pure LDS-read + plain float4 stores ----
    const size_t MK = (size_t)MQ * K_NEIGH;
    const int CO   = use_xyz ? (CCH + 3) : CCH;
    const int coff = use_xyz ? 3 : 0;
    float* o0 = out0 + ((size_t)b * CO + coff + c0) * MK;
    float* o1 = o0 + MK;

    #pragma unroll
    for (int i = 0; i < 16; ++i) {
        const int p = i * 4096 + 4 * t;      // flat (m,k) base, k-aligned x4
        const int4 j4 = jj[i];
        float4 s0, s1;
        s0.x = sf[j4.x]; s0.y = sf[j4.y]; s0.z = sf[j4.z]; s0.w = sf[j4.w];
        s1.x = sf[NPTS + j4.x]; s1.y = sf[NPTS + j4.y];
        s1.z = sf[NPTS + j4.z]; s1.w = sf[NPTS + j4.w];
        *(float4*)(o0 + p) = s0;
        *(float4*)(o1 + p) = s1;
    }
}

// Fallback gather (any shape): R1 structure.
__global__ __launch_bounds__(256) void gather_kernel(
    const float* __restrict__ xyz, const float* __restrict__ new_xyz,
    const float* __restrict__ feat, const int* __restrict__ idxb,
    float* __restrict__ out0, float* __restrict__ out1,
    int N, int M, int C, int use_xyz)
{
    const int tid = threadIdx.x;
    const int k = tid & 31;
    const int mloc = tid >> 5;
    const int mchunks = M >> 3;
    const int b = blockIdx.x / mchunks;
    const int m = (blockIdx.x - b * mchunks) * 8 + mloc;
    const int q = b * M + m;
    const int j = idxb[(size_t)q * K_NEIGH + k];
    const size_t xb = (size_t)b * 3 * N;
    const size_t nb = (size_t)b * 3 * M;
    const float gx = xyz[xb + j]         - new_xyz[nb + m];
    const float gy = xyz[xb + N + j]     - new_xyz[nb + M + m];
    const float gz = xyz[xb + 2 * N + j] - new_xyz[nb + 2 * M + m];
    const size_t MK = (size_t)M * K_NEIGH;
    const size_t o1 = (size_t)b * 3 * MK + (size_t)m * K_NEIGH + k;
    out1[o1] = gx; out1[o1 + MK] = gy; out1[o1 + 2 * MK] = gz;
    const int CO = use_xyz ? (C + 3) : C;
    size_t o0 = (size_t)b * CO * MK + (size_t)m * K_NEIGH + k;
    if (use_xyz) {
        out0[o0] = gx; out0[o0 + MK] = gy; out0[o0 + 2 * MK] = gz;
        o0 += 3 * MK;
    }
    const float* fb = feat + (size_t)b * C * N;
    #pragma unroll 4
    for (int c = 0; c < C; c += 4) {
        const float v0 = fb[(size_t)c * N + j];
        const float v1 = fb[(size_t)(c + 1) * N + j];
        const float v2 = fb[(size_t)(c + 2) * N + j];
        const float v3 = fb[(size_t)(c + 3) * N + j];
        out0[o0 + (size_t)c * MK]       = v0;
        out0[o0 + (size_t)(c + 1) * MK] = v1;
        out0[o0 + (size_t)(c + 2) * MK] = v2;
        out0[o0 + (size_t)(c + 3) * MK] = v3;
    }
}

extern "C" void kernel_launch(void* const* d_in, const int* in_sizes, int n_in,
                              void* d_out, int out_size, void* d_ws, size_t ws_size,
                              hipStream_t stream) {
    const float* new_xyz = (const float*)d_in[0];   // (B,3,M)
    const float* xyz     = (const float*)d_in[1];   // (B,3,N)
    const float* feat    = (const float*)d_in[2];   // (B,C,N)

    const int B = 4;                       // fixed by harness setup
    const int M = in_sizes[0] / (3 * B);   // 2048
    const int N = in_sizes[1] / (3 * B);   // 8192
    const int C = in_sizes[2] / (B * N);   // 128

    const long long sz_with = (long long)B * (C + 6) * M * K_NEIGH;
    const int use_xyz = (out_size == sz_with) ? 1 : 0;

    float* out0 = (float*)d_out;
    float* out1 = out0 + (size_t)B * (use_xyz ? (C + 3) : C) * M * K_NEIGH;

    // ws layout: idxb (1MB) | binned (B*N*16B = 512KB) | binStart (B*17 ints)
    int* idxb = (int*)d_ws;
    const size_t idx_bytes  = (size_t)B * M * K_NEIGH * sizeof(int);
    float4* binned = (float4*)((char*)d_ws + idx_bytes);
    const size_t bin_bytes  = (size_t)B * N * sizeof(float4);
    int* binStart = (int*)((char*)d_ws + idx_bytes + bin_bytes);
    const size_t bs_bytes   = (size_t)B * (NBIN + 1) * sizeof(int);

    const bool fast = (B == 4) && (N == NPTS) && (M == MQ) && (C == CCH)
                      && (ws_size >= idx_bytes + bin_bytes + bs_bytes);

    if (fast) {
        bin_points_kernel<<<B, 1024, 0, stream>>>(xyz, binned, binStart);
        ball_binned_kernel<<<(B * MQ) / 4, 256, 0, stream>>>(
            xyz, new_xyz, binned, binStart, idxb, out0, out1, use_xyz);
        gather_onepass_kernel<<<256, 1024, 0, stream>>>(feat, idxb, out0, use_xyz);
    } else {
        ball_query_xyz_kernel<<<(B * M) / 4, 256, 0, stream>>>(
            xyz, new_xyz, idxb, out0, out1, N, M, C, use_xyz);
        gather_kernel<<<B * (M / 8), 256, 0, stream>>>(xyz, new_xyz, feat, idxb,
                                                       out0, out1, N, M, C, use_xyz);
    }
}